// Round 7
// baseline (1658.135 us; speedup 1.0000x reference)
//
#include <hip/hip_runtime.h>

typedef _Float16 half8 __attribute__((ext_vector_type(8)));
typedef _Float16 half4 __attribute__((ext_vector_type(4)));
typedef float    f32x4 __attribute__((ext_vector_type(4)));
typedef unsigned long long u64x2 __attribute__((ext_vector_type(2)));

constexpr int Bt   = 256;   // batch
constexpr int Hd   = 1024;  // hidden
constexpr int G4   = 4096;  // 4*H
constexpr int Ts   = 128;   // time steps
constexpr int DOUT = 128;

constexpr int NGROUP   = 8;    // independent batch groups
constexpr int WG_PER_G = 32;   // WGs per group
constexpr int NWG      = NGROUP * WG_PER_G;  // 256
constexpr int NTHR     = 512;  // 8 waves
constexpr int GROWS    = 32;   // rows per group = 4 sub-blocks x 8

// seq layout: [t][jb 0..31][256 rows][32 cols] f16  (step stride = 512 KB)
constexpr size_t SEQ_T = (size_t)32 * 256 * 64;

// workspace layout (bytes)
constexpr size_t OFF_WSUM = 0;                                // [4096][1024] f16
constexpr size_t OFF_WIH  = OFF_WSUM + (size_t)G4 * Hd * 2;   // [4096][1024] f16
constexpr size_t OFF_WOUT = OFF_WIH  + (size_t)G4 * Hd * 2;   // [128][1024] f16
constexpr size_t OFF_X    = OFF_WOUT + (size_t)DOUT * Hd * 2; // blocked [32][256][32] f16
constexpr size_t OFF_BSUM = OFF_X    + (size_t)Bt * Hd * 2;   // [4096] f32
constexpr size_t OFF_BAR  = OFF_BSUM + (size_t)G4 * 4;        // counters: 8g x 4S x 128t x 128B
constexpr size_t BAR_SZ   = (size_t)NGROUP * 4 * Ts * 128;    // 524288
constexpr size_t OFF_SEQ  = OFF_BAR  + BAR_SZ;
constexpr size_t WS_NEED  = OFF_SEQ  + (size_t)Ts * SEQ_T;

__device__ __forceinline__ float fast_sig(float x) {
    return 1.f / (1.f + __expf(-x));
}
__device__ __forceinline__ float fast_tanh(float x) {
    float ax = fabsf(x);
    float e  = __expf(-2.f * ax);
    float t  = (1.f - e) / (1.f + e);
    return copysignf(t, x);
}

__device__ __forceinline__ void gload_lds16(const void* g, void* l) {
    __builtin_amdgcn_global_load_lds(
        (const __attribute__((address_space(1))) void*)g,
        (__attribute__((address_space(3))) void*)l, 16, 0, 0);
}
__device__ __forceinline__ void store16_wt(void* gp, u64x2 v) {
    asm volatile("global_store_dwordx4 %0, %1, off sc0 sc1"
                 :: "v"(gp), "v"(v) : "memory");
}
__device__ __forceinline__ unsigned load4_cp(const unsigned* gp) {
    unsigned v;
    asm volatile("global_load_dword %0, %1, off sc0 sc1\n\t"
                 "s_waitcnt vmcnt(0)"
                 : "=v"(v) : "v"(gp) : "memory");
    return v;
}
__device__ __forceinline__ void atomic_add_nr(unsigned* gp, unsigned v) {
    asm volatile("global_atomic_add %0, %1, off"
                 :: "v"(gp), "v"(v) : "memory");
}

// ---------------- precompute ----------------
__global__ void prep_kernel(const float* __restrict__ Wih, const float* __restrict__ Whh,
                            const float* __restrict__ bih, const float* __restrict__ bhh,
                            const float* __restrict__ x,   const float* __restrict__ Wout,
                            _Float16* __restrict__ wsum16, _Float16* __restrict__ wih16,
                            _Float16* __restrict__ wout16, _Float16* __restrict__ x16,
                            float* __restrict__ bsum, unsigned* __restrict__ bar) {
    const int i0     = blockIdx.x * blockDim.x + threadIdx.x;
    const int stride = gridDim.x * blockDim.x;

    for (int i = i0; i < G4 * Hd / 4; i += stride) {
        f32x4 a = ((const f32x4*)Wih)[i];
        f32x4 b = ((const f32x4*)Whh)[i];
        half4 hs, hi;
        #pragma unroll
        for (int j = 0; j < 4; ++j) {
            hs[j] = (_Float16)(a[j] + b[j]);
            hi[j] = (_Float16)a[j];
        }
        ((half4*)wsum16)[i] = hs;
        ((half4*)wih16)[i]  = hi;
    }
    for (int i = i0; i < DOUT * Hd / 4; i += stride) {
        f32x4 a = ((const f32x4*)Wout)[i];
        half4 h;
        #pragma unroll
        for (int j = 0; j < 4; ++j) h[j] = (_Float16)a[j];
        ((half4*)wout16)[i] = h;
    }
    // x -> blocked f16 layout [jb][256 rows][32 cols]
    for (int i = i0; i < Bt * Hd / 4; i += stride) {
        f32x4 a = ((const f32x4*)x)[i];
        half4 h;
        #pragma unroll
        for (int j = 0; j < 4; ++j) h[j] = (_Float16)a[j];
        const int row = i >> 8;
        const int e   = (i & 255) * 4;
        const int jb  = e >> 5;
        const int c   = e & 31;
        ((half4*)x16)[(jb * 256 + row) * 8 + (c >> 2)] = h;
    }
    for (int i = i0; i < G4; i += stride) bsum[i] = bih[i] + bhh[i];
    // zero the counters at the coherence point
    for (int i = i0; i < (int)(BAR_SZ / 4); i += stride)
        __hip_atomic_store(bar + i, 0u, __ATOMIC_RELAXED, __HIP_MEMORY_SCOPE_AGENT);
}

// ---------------- persistent 4-deep pipelined LSTM ----------------
// group g=bid&7 owns rows [g*32,+32) as 4 sub-blocks S of 8 rows.
// WG wgi=bid>>3 covers j-cols [wgi*32,+32). 8 waves = 4 K-splits x 2 jg.
// Per phase (S,t): mfma S | dump partials + poll next stage's counter |
// stage S+1, leads reduce+cell+WT-store h; counter-add DEFERRED one phase.
__launch_bounds__(NTHR, 2)
__global__ void lstm_kernel(const _Float16* __restrict__ wsum16,
                            const _Float16* __restrict__ wih16,
                            const _Float16* __restrict__ wout16,
                            const _Float16* __restrict__ x16,
                            const float* __restrict__ bsum,
                            const float* __restrict__ bout,
                            _Float16* __restrict__ seq,
                            float* __restrict__ out,
                            unsigned* __restrict__ bar) {
    __shared__ char smem[65536];  // 4 regions of 16KB: A-tile 8x2048B; region (S+2)&3 doubles as dump+hst

    const int bid = blockIdx.x;
    const int g   = bid & 7;
    const int wgi = bid >> 3;
    const int tid = threadIdx.x;
    const int wv  = tid >> 6;
    const int l   = tid & 63;
    const int lr  = l & 15;
    const int lk  = l >> 4;
    const int ks  = wv & 3;            // K-split (256-wide)
    const int jg  = wv >> 2;           // 0..1
    const int j0  = wgi * 32 + jg * 16;
    const int brow0 = g * GROWS;
    const bool lead = (ks == 0);

    auto cptr = [&](int S, int tt) -> unsigned* {
        return bar + (((size_t)(g * 4 + S) * Ts + tt) << 5);
    };

    float bias[4];
    #pragma unroll
    for (int gg = 0; gg < 4; ++gg) bias[gg] = bsum[gg * Hd + j0 + lr];

    half8 Bf[4][8];
    auto loadB = [&](const _Float16* __restrict__ W) {
        #pragma unroll
        for (int gg = 0; gg < 4; ++gg)
            #pragma unroll
            for (int kk = 0; kk < 8; ++kk)
                Bf[gg][kk] = *(const half8*)(W + (size_t)(gg * Hd + j0 + lr) * Hd
                                               + ks * 256 + kk * 32 + lk * 8);
    };

    const char* x16c = (const char*)x16;
    char*       seqc = (char*)seq;

    // stage 8 rows x 1024 cols (16KB) from blocked src, XOR-swizzled 16B blocks
    auto stageS = [&](char* Abase, const char* srcb, int rbase) {
        #pragma unroll
        for (int s = 0; s < 2; ++s) {
            const int i   = wv * 2 + s;             // 0..15 chunks of 1KB
            const int row = i >> 1;                 // 0..7
            const int gb  = ((i & 1) * 64 + l) ^ (row & 7);
            const int jb  = gb >> 2;
            const int q   = gb & 3;
            gload_lds16(srcb + ((size_t)(jb * 256 + rbase + row)) * 64 + q * 16,
                        Abase + i * 1024);
        }
    };

    f32x4 c[4];
    #pragma unroll
    for (int S = 0; S < 4; ++S) c[S] = f32x4{0.f,0.f,0.f,0.f};

    loadB(wih16);
    stageS(smem, x16c, brow0);   // A[0] <- x rows [brow0, +8)
    __syncthreads();

    #pragma unroll 1
    for (int t4 = 0; t4 < Ts; ++t4) {
        #pragma unroll
        for (int S = 0; S < 4; ++S) {
            char* A    = smem + S * 16384;
            char* Anx  = smem + ((S + 1) & 3) * 16384;
            char* Admp = smem + ((S + 2) & 3) * 16384;
            const int  p        = t4 * 4 + S;
            const int  tp       = (S == 3) ? t4 + 1 : t4;   // stage-target step
            const bool do_stage = (p != Ts * 4 - 1);

            // ---- sect1: MFMA over A[S] (rows 8, lr&7 duplicates upper half) ----
            f32x4 acc[4];
            #pragma unroll
            for (int gg = 0; gg < 4; ++gg) acc[gg] = f32x4{0.f,0.f,0.f,0.f};
            #pragma unroll
            for (int kk = 0; kk < 8; ++kk) {
                const int bb = (ks * 32 + kk * 4 + lk) ^ (lr & 7);
                half8 a = *(const half8*)(A + (lr & 7) * 2048 + bb * 16);
                #pragma unroll
                for (int gg = 0; gg < 4; ++gg)
                    acc[gg] = __builtin_amdgcn_mfma_f32_16x16x32_f16(a, Bf[gg][kk], acc[gg], 0,0,0);
            }
            __syncthreads();

            // ---- sect2: dumps + poll ----
            if (!lead) {
                if (lk < 2) {
                    char* dst = Admp + (jg * 3 + ks - 1) * 2048;
                    #pragma unroll
                    for (int gg = 0; gg < 4; ++gg)
                        *(f32x4*)(dst + gg * 512 + lr * 32 + lk * 16) = acc[gg];
                }
                if (wv == 1 && do_stage && tp >= 1) {
                    unsigned* cp = cptr((S + 1) & 3, tp - 1);
                    while (load4_cp(cp) < 64u) __builtin_amdgcn_s_sleep(1);
                }
            }
            __syncthreads();

            // ---- sect3: deferred counter, stage next, leads finish ----
            if (lead && l == 0 && p > 0)   // flag for PREVIOUS phase (stores drained by last barrier)
                atomic_add_nr(cptr((S + 3) & 3, (S == 0) ? t4 - 1 : t4), 1u);

            if (do_stage) {
                const char* src = (tp == 0) ? x16c : (seqc + (size_t)(tp - 1) * SEQ_T);
                stageS(Anx, src, brow0 + ((S + 1) & 3) * 8);
            }

            if (lead && lk < 2) {
                #pragma unroll
                for (int s = 0; s < 3; ++s) {
                    const char* srcd = Admp + (jg * 3 + s) * 2048;
                    #pragma unroll
                    for (int gg = 0; gg < 4; ++gg)
                        acc[gg] += *(const f32x4*)(srcd + gg * 512 + lr * 32 + lk * 16);
                }
                char* hst = Admp + 12288 + jg * 256;   // [8 rows][16 cols] f16
                #pragma unroll
                for (int r = 0; r < 4; ++r) {
                    float ig = fast_sig (acc[0][r] + bias[0]);
                    float fg = fast_sig (acc[1][r] + bias[1]);
                    float gv = fast_tanh(acc[2][r] + bias[2]);
                    float og = fast_sig (acc[3][r] + bias[3]);
                    float cn = fg * c[S][r] + ig * gv;
                    c[S][r] = cn;
                    float hv = og * fast_tanh(cn);
                    *(_Float16*)(hst + (lk * 4 + r) * 32 + lr * 2) = (_Float16)hv;
                }
            }
            if (lead) {
                asm volatile("s_waitcnt lgkmcnt(0)" ::: "memory");  // hst visible wave-wide
                if (l < 16) {
                    const char* hst = Admp + 12288 + jg * 256;
                    u64x2 v = *(const u64x2*)(hst + (l >> 1) * 32 + (l & 1) * 16);
                    char* gp = seqc + (size_t)t4 * SEQ_T
                             + ((size_t)(wgi * 256 + brow0 + S * 8 + (l >> 1))) * 64
                             + jg * 32 + (l & 1) * 16;
                    store16_wt(gp, v);
                }
            }
            if (t4 == 0 && S == 3) loadB(wsum16);
            __syncthreads();   // drains stage loads + h stores + atomics
        }
    }

    // final counter for (S=3, t=127)
    if (lead) {
        asm volatile("s_waitcnt vmcnt(0)" ::: "memory");
        if (l == 0) atomic_add_nr(cptr(3, Ts - 1), 1u);
    }
    // wait own group fully done (all 4 sub-blocks at t=127)
    if (wv == 0) {
        unsigned* cp = cptr(l & 3, Ts - 1);
        while (true) {
            unsigned v = load4_cp(cp);
            if (__all(v >= 64u)) break;
            __builtin_amdgcn_s_sleep(1);
        }
    }
    __syncthreads();

    // ---------------- fused output projection (group-local rows) ----------------
    {
        const int idx  = wgi * 8 + wv;          // 0..255
        const int t_   = idx >> 1;              // 0..127
        const int bb16 = brow0 + (idx & 1) * 16;
        const int row  = bb16 + lr;
        const char* ab = seqc + (size_t)t_ * SEQ_T + (size_t)row * 64 + lk * 16;

        f32x4 oacc[8];
        #pragma unroll
        for (int ni = 0; ni < 8; ++ni) oacc[ni] = f32x4{0.f,0.f,0.f,0.f};

        #pragma unroll 2
        for (int k0 = 0; k0 < Hd; k0 += 32) {
            half8 a = *(const half8*)(ab + (size_t)k0 * 512);  // jb blocks
            #pragma unroll
            for (int ni = 0; ni < 8; ++ni) {
                half8 bf = *(const half8*)(wout16 + (size_t)(ni * 16 + lr) * Hd + lk * 8 + k0);
                oacc[ni] = __builtin_amdgcn_mfma_f32_16x16x32_f16(a, bf, oacc[ni], 0,0,0);
            }
        }
        #pragma unroll
        for (int ni = 0; ni < 8; ++ni) {
            const int d  = ni * 16 + lr;
            const float bo = bout[d];
            #pragma unroll
            for (int r = 0; r < 4; ++r) {
                const int b = bb16 + lk * 4 + r;
                out[(size_t)b * (Ts * DOUT) + t_ * DOUT + d] = oacc[ni][r] + bo;
            }
        }
    }
}

extern "C" void kernel_launch(void* const* d_in, const int* in_sizes, int n_in,
                              void* d_out, int out_size, void* d_ws, size_t ws_size,
                              hipStream_t stream) {
    const float* x    = (const float*)d_in[0];
    const float* Wih  = (const float*)d_in[1];
    const float* Whh  = (const float*)d_in[2];
    const float* bih  = (const float*)d_in[3];
    const float* bhh  = (const float*)d_in[4];
    const float* Wout = (const float*)d_in[5];
    const float* bout = (const float*)d_in[6];

    if (ws_size < WS_NEED) return;

    char* ws = (char*)d_ws;
    _Float16* wsum16 = (_Float16*)(ws + OFF_WSUM);
    _Float16* wih16  = (_Float16*)(ws + OFF_WIH);
    _Float16* wout16 = (_Float16*)(ws + OFF_WOUT);
    _Float16* x16    = (_Float16*)(ws + OFF_X);
    float*    bsum   = (float*)(ws + OFF_BSUM);
    unsigned* bar    = (unsigned*)(ws + OFF_BAR);
    _Float16* seq    = (_Float16*)(ws + OFF_SEQ);
    float*    outp   = (float*)d_out;

    hipLaunchKernelGGL(prep_kernel, dim3(1024), dim3(256), 0, stream,
                       Wih, Whh, bih, bhh, x, Wout,
                       wsum16, wih16, wout16, x16, bsum, bar);

    void* args[] = { &wsum16, &wih16, &wout16, &x16, &bsum,
                     (void*)&bout, &seq, &outp, &bar };
    hipLaunchCooperativeKernel((void*)lstm_kernel, dim3(NWG), dim3(NTHR),
                               args, 0, stream);
}